// Round 5
// baseline (327.928 us; speedup 1.0000x reference)
//
#include <hip/hip_runtime.h>

// Adder: base-10 digit addition with carry-lookahead.
// (B=524288, S=64) fp32 digits, index 0 = MSB, 63 = LSB.
// Mapping: one wave covers 4 rows per "unit" (unit = 256 floats = 1 KiB/array):
//   row r = lanes 16r..16r+15, lane j-of-row holds digits 4j..4j+3 (float4).
// Carry chain closed-form (verified exact, absmax 0 in R1/R3/R4):
//   digit: g=(s>=10), p=(s==9); lane: 4-bit lookahead; row: ballot pair +
//   16-bit lookahead, bit-reversed to LSB-first, top carry dropped.
//
// R4 post-mortem: VGPR_Count=32 proved the compiler never pipelined the
// unrolled loop -> 1 load-pair in flight per wave -> ~2.3 TB/s. This version
// forces a 4-deep explicit prefetch ring in registers (8 dwordx4 loads in
// flight per wave) with the loop fully unrolled so ring slots are static.

typedef float f32x4 __attribute__((ext_vector_type(4)));

constexpr int       BLOCKS         = 2048;
constexpr int       THREADS        = 256;
constexpr int       WAVES          = BLOCKS * (THREADS / 64);   // 8192
constexpr long long N_UNITS        = 524288LL * 64 / 256;       // 131072
constexpr int       UNITS_PER_WAVE = (int)(N_UNITS / WAVES);    // 16
constexpr int       PIPE           = 4;                         // ring depth

__global__ __launch_bounds__(THREADS) void adder_kernel(
    const float* __restrict__ a,
    const float* __restrict__ b,
    float* __restrict__ out)
{
    const int lane = (int)(threadIdx.x & 63);
    const int wid  = (int)(blockIdx.x * 4 + (threadIdx.x >> 6));
    const int r    = lane >> 4;    // row within wave's 4-row unit
    const int j    = lane & 15;    // group index in row, j=0 most significant
    const long long laneoff = 4 * lane;

    f32x4 va[PIPE], vb[PIPE];

    // prime the pipeline: 4 unit-pairs (8 dwordx4 loads) in flight
#pragma unroll
    for (int p = 0; p < PIPE; ++p) {
        const long long base = ((long long)p * WAVES + wid) * 256 + laneoff;
        va[p] = *(const f32x4*)(a + base);
        vb[p] = *(const f32x4*)(b + base);
    }

#pragma unroll
    for (int i = 0; i < UNITS_PER_WAVE; ++i) {
        const int slot = i & (PIPE - 1);
        const f32x4 av = va[slot];   // waits on load issued PIPE iters ago
        const f32x4 bv = vb[slot];

        // refill the slot BEFORE computing: keeps 4 pairs in flight
        if (i + PIPE < UNITS_PER_WAVE) {
            const long long nbase =
                ((long long)(i + PIPE) * WAVES + wid) * 256 + laneoff;
            va[slot] = *(const f32x4*)(a + nbase);
            vb[slot] = *(const f32x4*)(b + nbase);
        }

        const float s0 = av.x + bv.x;   // most significant of lane's group
        const float s1 = av.y + bv.y;
        const float s2 = av.z + bv.z;
        const float s3 = av.w + bv.w;   // least significant

        // 4-bit masks, LSB-first in group: bit0<->s3 ... bit3<->s0
        const unsigned g4 = (unsigned)(s3 >= 10.0f)
                          | ((unsigned)(s2 >= 10.0f) << 1)
                          | ((unsigned)(s1 >= 10.0f) << 2)
                          | ((unsigned)(s0 >= 10.0f) << 3);
        const unsigned p4 = (unsigned)(s3 == 9.0f)
                          | ((unsigned)(s2 == 9.0f) << 1)
                          | ((unsigned)(s1 == 9.0f) << 2)
                          | ((unsigned)(s0 == 9.0f) << 3);
        const unsigned pg4 = p4 | g4;
        const unsigned c4  = (pg4 + g4) ^ pg4 ^ g4;  // bit4 = group generate
        const bool Ggrp = (c4 >> 4) & 1u;
        const bool Pgrp = (p4 == 0xFu);

        const unsigned long long Gl = __ballot(Ggrp);
        const unsigned long long Pl = __ballot(Pgrp);

        unsigned Gr = (unsigned)((Gl >> (16 * r)) & 0xFFFFull);
        unsigned Pr = (unsigned)((Pl >> (16 * r)) & 0xFFFFull);
        Gr = __brev(Gr) >> 16;           // lane j <-> LSB-first pos 15-j
        Pr = __brev(Pr) >> 16;
        const unsigned PGr = Pr | Gr;
        const unsigned Cr  = (PGr + Gr) ^ PGr ^ Gr;  // carry-in per group

        const float cin = (float)((Cr >> (15 - j)) & 1u);

        // serial ripple through the lane's 4 digits, LSB (s3) first
        float u, c;
        f32x4 d;
        u = s3 + cin; c = (u >= 10.0f) ? 1.0f : 0.0f; d.w = u - 10.0f * c;
        u = s2 + c;   c = (u >= 10.0f) ? 1.0f : 0.0f; d.z = u - 10.0f * c;
        u = s1 + c;   c = (u >= 10.0f) ? 1.0f : 0.0f; d.y = u - 10.0f * c;
        u = s0 + c;   c = (u >= 10.0f) ? 1.0f : 0.0f; d.x = u - 10.0f * c;

        const long long base = ((long long)i * WAVES + wid) * 256 + laneoff;
        *(f32x4*)(out + base) = d;
    }
}

extern "C" void kernel_launch(void* const* d_in, const int* in_sizes, int n_in,
                              void* d_out, int out_size, void* d_ws, size_t ws_size,
                              hipStream_t stream) {
    const float* a = (const float*)d_in[0];
    const float* b = (const float*)d_in[1];
    float* out = (float*)d_out;
    adder_kernel<<<BLOCKS, THREADS, 0, stream>>>(a, b, out);
}

// Round 6
// 323.575 us; speedup vs baseline: 1.0135x; 1.0135x over previous
//
#include <hip/hip_runtime.h>

// Adder: base-10 digit addition with carry, one wave (64 lanes) per row.
// Row layout: index 0 = most-significant digit, index 63 = least-significant.
// Carry chain solved in closed form via ballot + 64-bit carry-lookahead:
//   g = (s >= 10)  generate, p = (s == 9) propagate  (mutually exclusive)
//   in LSB-first bit order, carry-in bits C = ((P|G)+G) ^ (P|G) ^ G
// Digits are exact small integers in fp32, so float compares are exact.
//
// R1-R5 post-mortem: four structures (scalar short-wave / float4 short-wave /
// persistent unrolled / persistent 4-deep prefetch ring) all pin at ~3.9 TB/s
// app-side with nothing saturated (VALU<=20%, occ 53-77%, FETCH/WRITE ideal,
// 8KB/wave outstanding in R5). Best was the simplest (R1, 104 us). This round:
// R1 structure + nontemporal hints on all three streams (read-once/write-once,
// zero reuse) + 1024-thread blocks (4x fewer WG dispatches, same wave count).

__global__ __launch_bounds__(1024) void adder_kernel(
    const float* __restrict__ a,
    const float* __restrict__ b,
    float* __restrict__ out)
{
    const int lane = (int)(threadIdx.x & 63);
    const long long row = (long long)blockIdx.x * 16 + (threadIdx.x >> 6);

    const long long idx = row * 64 + lane;   // wave: 256B contiguous
    // read-once streams: nontemporal (no-allocate / evict-first) hints
    const float av = __builtin_nontemporal_load(a + idx);
    const float bv = __builtin_nontemporal_load(b + idx);
    const float s = av + bv;                 // 0..18, exact integer

    // lane-space masks (bit l = lane l = digit index l; index 63 is LSB)
    const unsigned long long g_l = __ballot(s >= 10.0f);
    const unsigned long long p_l = __ballot(s == 9.0f);

    // reverse into LSB-first position space (position k = 63 - lane)
    const unsigned long long G  = __brevll(g_l);
    const unsigned long long P  = __brevll(p_l);
    const unsigned long long PG = P | G;
    const unsigned long long C_pos = (PG + G) ^ PG ^ G;  // carry-in per position
    const unsigned long long C_l   = __brevll(C_pos);    // back to lane space

    const float cin = (float)((C_l >> lane) & 1ULL);
    const float u = s + cin;                  // 0..19
    const float carry_out = (u >= 10.0f) ? 1.0f : 0.0f;
    __builtin_nontemporal_store(u - 10.0f * carry_out, out + idx);
}

extern "C" void kernel_launch(void* const* d_in, const int* in_sizes, int n_in,
                              void* d_out, int out_size, void* d_ws, size_t ws_size,
                              hipStream_t stream) {
    const float* a = (const float*)d_in[0];
    const float* b = (const float*)d_in[1];
    float* out = (float*)d_out;

    // 524288 rows, 16 rows (waves) per 1024-thread block -> 32768 blocks
    const long long n_rows = (long long)in_sizes[0] / 64;
    const int blocks = (int)(n_rows / 16);
    adder_kernel<<<blocks, 1024, 0, stream>>>(a, b, out);
}